// Round 1
// 291.144 us; speedup vs baseline: 1.0966x; 1.0966x over previous
//
#include <hip/hip_runtime.h>
#include <math.h>

#define CH 4096        // edges per partition block
#define NBUK_MAX 256   // max buckets (N <= 131072)
#define MAXB 12288     // max edges per bucket staged in LDS (48 KB)
#define SRC_BITS 17    // N < 131072 fits in 17 bits

typedef short bf16x8 __attribute__((ext_vector_type(8)));
typedef float f32x4 __attribute__((ext_vector_type(4)));
typedef float f32x2 __attribute__((ext_vector_type(2)));

// bf16 <-> f32 helpers (RNE pack; exact unpack)
__device__ __forceinline__ unsigned short f2bf(float f) {
    union { float f; unsigned int u; } v; v.f = f;
    unsigned int r = (v.u + 0x7FFFu + ((v.u >> 16) & 1u)) >> 16;
    return (unsigned short)r;
}
__device__ __forceinline__ float bf2f(unsigned short u) {
    union { unsigned int u; float f; } v; v.u = ((unsigned int)u) << 16;
    return v.f;
}
// unpack packed pair (low ushort = even feature, high = odd)
__device__ __forceinline__ float bflo(unsigned int u) {
    union { unsigned int u; float f; } v; v.u = u << 16;
    return v.f;
}
__device__ __forceinline__ float bfhi(unsigned int u) {
    union { unsigned int u; float f; } v; v.u = u & 0xFFFF0000u;
    return v.f;
}

// ---------------- P1a: per-block bucket histograms ----------------
__global__ __launch_bounds__(256) void p1a_kernel(const int* __restrict__ src, const int* __restrict__ dst,
                                                  int* __restrict__ mat, int E, int B1, int nbuk) {
    __shared__ int hd[NBUK_MAX], hs[NBUK_MAX];
    const int t = threadIdx.x;
    if (t < nbuk) { hd[t] = 0; hs[t] = 0; }
    __syncthreads();
    const int base = blockIdx.x * CH;
    const int cnt = min(CH, E - base);
    for (int k = t; k < cnt; k += 256) {
        int d = dst[base + k];
        int s = src[base + k];
        atomicAdd(&hd[d >> 9], 1);
        atomicAdd(&hs[s >> 9], 1);
    }
    __syncthreads();
    if (t < nbuk) {
        mat[t * B1 + blockIdx.x] = hd[t];
        mat[(nbuk + t) * B1 + blockIdx.x] = hs[t];
    }
}

// ---------------- 3-phase exclusive scan ----------------
__global__ __launch_bounds__(256) void scan1_kernel(const int* __restrict__ cnt,
                                                    int* __restrict__ seg,
                                                    int* __restrict__ bsums, int N) {
    __shared__ int tsum[256];
    const int t = threadIdx.x;
    const int base = blockIdx.x * 1024 + t * 4;
    int v0 = (base + 0 < N) ? cnt[base + 0] : 0;
    int v1 = (base + 1 < N) ? cnt[base + 1] : 0;
    int v2 = (base + 2 < N) ? cnt[base + 2] : 0;
    int v3 = (base + 3 < N) ? cnt[base + 3] : 0;
    tsum[t] = v0 + v1 + v2 + v3;
    __syncthreads();
    for (int off = 1; off < 256; off <<= 1) {
        int x = (t >= off) ? tsum[t - off] : 0;
        __syncthreads();
        if (t >= off) tsum[t] += x;
        __syncthreads();
    }
    int run = (t > 0) ? tsum[t - 1] : 0;
    if (base + 0 < N) seg[base + 0] = run; run += v0;
    if (base + 1 < N) seg[base + 1] = run; run += v1;
    if (base + 2 < N) seg[base + 2] = run; run += v2;
    if (base + 3 < N) seg[base + 3] = run;
    if (t == 255) bsums[blockIdx.x] = tsum[255];
}

__global__ void scan2_kernel(int* __restrict__ bsums, int* __restrict__ seg, int N, int G) {
    __shared__ int s[256];
    int t = threadIdx.x;
    if (t < G) s[t] = bsums[t];
    __syncthreads();
    if (t == 0) {
        int run = 0;
        for (int i = 0; i < G; ++i) { int v = s[i]; s[i] = run; run += v; }
        seg[N] = run;
    }
    __syncthreads();
    if (t < G) bsums[t] = s[t];
}

__global__ __launch_bounds__(256) void scan3_kernel(int* __restrict__ seg,
                                                    const int* __restrict__ bsums, int N) {
    int add = bsums[blockIdx.x];
    int base = blockIdx.x * 1024 + threadIdx.x * 4;
#pragma unroll
    for (int i = 0; i < 4; ++i) {
        int idx = base + i;
        if (idx < N) seg[idx] += add;
    }
}

// ---------------- P1c: LDS-staged partition scatter ----------------
// histograms are NOT recomputed: p1a already wrote them to mat.
__global__ __launch_bounds__(256) void p1c_kernel(const int* __restrict__ src, const int* __restrict__ dst,
                                                  const int* __restrict__ mat,
                                                  const int* __restrict__ scan,
                                                  int* __restrict__ pedge,
                                                  int E, int B1, int nbuk) {
    __shared__ int hd[NBUK_MAX], hs[NBUK_MAX];
    __shared__ int curD[NBUK_MAX], curS[NBUK_MAX];
    __shared__ int baseD[NBUK_MAX], baseS[NBUK_MAX];
    __shared__ int stD[CH];
    __shared__ int stS[CH];
    const int t = threadIdx.x;
    if (t < nbuk) {
        hd[t] = mat[t * B1 + blockIdx.x];
        hs[t] = mat[(nbuk + t) * B1 + blockIdx.x];
    }
    const int base = blockIdx.x * CH;
    const int cnt = min(CH, E - base);
    int dl[CH / 256], sl[CH / 256];
#pragma unroll
    for (int k = 0; k < CH / 256; ++k) {
        int i = t + k * 256;
        if (i < cnt) {
            dl[k] = dst[base + i];
            sl[k] = src[base + i];
        }
    }
    __syncthreads();
    for (int off = 1; off < nbuk; off <<= 1) {
        int v0 = (t >= off && t < nbuk) ? hd[t - off] : 0;
        int w0 = (t >= off && t < nbuk) ? hs[t - off] : 0;
        __syncthreads();
        if (t < nbuk) { hd[t] += v0; hs[t] += w0; }
        __syncthreads();
    }
    if (t < nbuk) {
        int excD = t ? hd[t - 1] : 0;
        int excS = t ? hs[t - 1] : 0;
        curD[t] = excD;
        curS[t] = excS;
        baseD[t] = scan[t * B1 + blockIdx.x] - excD;
        baseS[t] = scan[(nbuk + t) * B1 + blockIdx.x] - excS;
    }
    __syncthreads();
#pragma unroll
    for (int k = 0; k < CH / 256; ++k) {
        int i = t + k * 256;
        if (i < cnt) {
            int j = dl[k] >> 9;
            int p = atomicAdd(&curD[j], 1);
            stD[p] = ((dl[k] & 511) << SRC_BITS) | sl[k];
            int jq = sl[k] >> 9;
            int q = atomicAdd(&curS[jq], 1);
            stS[q] = sl[k];
        }
    }
    __syncthreads();
    for (int i = t; i < cnt; i += 256) {
        int lo = 0, hi = nbuk - 1;
        while (lo < hi) { int mid = (lo + hi) >> 1; if (hd[mid] > i) hi = mid; else lo = mid + 1; }
        pedge[baseD[lo] + i] = stD[i];
        int lo2 = 0, hi2 = nbuk - 1;
        while (lo2 < hi2) { int mid = (lo2 + hi2) >> 1; if (hs[mid] > i) hi2 = mid; else lo2 = mid + 1; }
        pedge[baseS[lo2] + i] = stS[i];
    }
}

// ---------------- P2+S2 merged: per-bucket sort / histograms ----------------
// blocks [0, nbuk)       : P2 role — local sort -> esrc, seg, norm_dst
// blocks [nbuk, 2*nbuk)  : S2 role — src histogram -> norm_src
// 512 threads: one bin per thread, 2.6x the parallelism of the old 196x256 pair.
__global__ __launch_bounds__(512) void p2s2_kernel(const int* __restrict__ pedge,
                                                   const int* __restrict__ scan,
                                                   int* __restrict__ esrc, int* __restrict__ seg,
                                                   float* __restrict__ norm_dst,
                                                   float* __restrict__ norm_src,
                                                   int N, int E, int B1, int nbuk) {
    __shared__ int h[512];
    __shared__ int cur[512];
    __shared__ int stage[MAXB];
    const int t = threadIdx.x;
    const int b0 = blockIdx.x;
    if (b0 >= nbuk) {
        // ---- S2 role ----
        const int b = b0 - nbuk;
        h[t] = 0;
        __syncthreads();
        const int sb0 = scan[(nbuk + b) * B1];
        const int sb1 = scan[(nbuk + b + 1) * B1];
        for (int i = sb0 + t; i < sb1; i += 512) atomicAdd(&h[pedge[i] & 511], 1);
        __syncthreads();
        int n = (b << 9) + t;
        if (n < N) norm_src[n] = rsqrtf(fmaxf((float)h[t], 1.0f));
        return;
    }
    // ---- P2 role ----
    const int b = b0;
    h[t] = 0;
    __syncthreads();
    const int bb0 = scan[b * B1];
    const int bb1 = scan[(b + 1) * B1];
    for (int i = bb0 + t; i < bb1; i += 512) atomicAdd(&h[(pedge[i] >> SRC_BITS) & 511], 1);
    __syncthreads();
    for (int off = 1; off < 512; off <<= 1) {
        int v = (t >= off) ? h[t - off] : 0;
        __syncthreads();
        h[t] += v;
        __syncthreads();
    }
    {
        int exc = t ? h[t - 1] : 0;
        cur[t] = exc;
        int n = (b << 9) + t;
        if (n < N) {
            seg[n] = bb0 + exc;
            norm_dst[n] = rsqrtf(fmaxf((float)(h[t] - exc), 1.0f));
        }
        if (b == 0 && t == 0) seg[N] = E;
    }
    __syncthreads();
    const int cnt = bb1 - bb0;
    for (int i = bb0 + t; i < bb1; i += 512) {
        int v = pedge[i];
        int j = (v >> SRC_BITS) & 511;
        int p = atomicAdd(&cur[j], 1);
        int s = v & ((1 << SRC_BITS) - 1);
        if (p < MAXB) stage[p] = s; else esrc[bb0 + p] = s;
    }
    __syncthreads();
    for (int i = t; i < cnt && i < MAXB; i += 512) esrc[bb0 + i] = stage[i];
}

// ---------------- X(bf16) = (H @ W) * norm_row  — MFMA split-bf16 ----------------
// Row N (one past the real nodes) is written as an all-zero row: segsum's
// branchless tail redirects out-of-range edge slots to it.
template<int K>
__global__ __launch_bounds__(256) void gemm_norm(const float* __restrict__ H,
                                                 const float* __restrict__ W,
                                                 const float* __restrict__ norm,
                                                 unsigned short* __restrict__ X, int N) {
    constexpr int KP = K + 8;  // padded stride (halves)
    __shared__ __align__(16) unsigned short sHi[64 * KP];
    __shared__ __align__(16) unsigned short sLo[64 * KP];
    const int tid = threadIdx.x;

    // stage W (row-major [K][64]) transposed, split hi/lo
    for (int idx = tid; idx < K * 64; idx += 256) {
        int k = idx >> 6;
        int c = idx & 63;
        float v = W[idx];
        unsigned short hi = f2bf(v);
        sHi[c * KP + k] = hi;
        sLo[c * KP + k] = f2bf(v - bf2f(hi));
    }
    __syncthreads();

    const int w = tid >> 6;
    const int lane = tid & 63;
    const int quad = lane >> 4;
    const int l16 = lane & 15;
    const int n0 = blockIdx.x * 64;
    const int arow = n0 + w * 16 + l16;
    const int arow_c = (arow < N) ? arow : (N - 1);
    const float* Hrow = H + (size_t)arow_c * K + quad * 8;

    f32x4 acc[4];
#pragma unroll
    for (int t = 0; t < 4; ++t) acc[t] = (f32x4){0.0f, 0.0f, 0.0f, 0.0f};

    float4 p0 = *(const float4*)(Hrow + 0);
    float4 p1 = *(const float4*)(Hrow + 4);

#pragma unroll
    for (int kc = 0; kc < K / 32; ++kc) {
        const float v[8] = {p0.x, p0.y, p0.z, p0.w, p1.x, p1.y, p1.z, p1.w};
        bf16x8 aHi, aLo;
#pragma unroll
        for (int j = 0; j < 8; ++j) {
            unsigned short hi = f2bf(v[j]);
            aHi[j] = (short)hi;
            aLo[j] = (short)f2bf(v[j] - bf2f(hi));
        }
        if (kc + 1 < K / 32) {
            p0 = *(const float4*)(Hrow + (kc + 1) * 32 + 0);
            p1 = *(const float4*)(Hrow + (kc + 1) * 32 + 4);
        }
        const int kbase = kc * 32 + quad * 8;
#pragma unroll
        for (int t = 0; t < 4; ++t) {
            const int col = t * 16 + l16;
            const bf16x8 bHi = *(const bf16x8*)&sHi[col * KP + kbase];
            const bf16x8 bLo = *(const bf16x8*)&sLo[col * KP + kbase];
            acc[t] = __builtin_amdgcn_mfma_f32_16x16x32_bf16(aLo, bHi, acc[t], 0, 0, 0);
            acc[t] = __builtin_amdgcn_mfma_f32_16x16x32_bf16(aHi, bLo, acc[t], 0, 0, 0);
            acc[t] = __builtin_amdgcn_mfma_f32_16x16x32_bf16(aHi, bHi, acc[t], 0, 0, 0);
        }
    }

#pragma unroll
    for (int r = 0; r < 4; ++r) {
        const int node = n0 + w * 16 + quad * 4 + r;
        if (node < N) {
            const float s = norm[node];
#pragma unroll
            for (int t = 0; t < 4; ++t) {
                X[(size_t)node * 64 + t * 16 + l16] = f2bf(acc[t][r] * s);
            }
        } else if (node == N) {
            // zero row for segsum's branchless tail redirect
#pragma unroll
            for (int t = 0; t < 4; ++t) {
                X[(size_t)node * 64 + t * 16 + l16] = 0;
            }
        }
    }
}

// ---------------- segment sum over CSR (bf16 X rows) + fused epilogue ----------------
// 16 lanes per row (uint2 = 4 bf16 each), 4 edge slots x 4 consecutive edges each:
// 16 edges per iteration, 4 independent gathers in flight per lane (MLP depth 4).
// Tail is branchless: out-of-range slots gather the all-zero row X[N] (L1-hot).
template<bool ELU>
__global__ __launch_bounds__(256) void segsum_kernel(const unsigned short* __restrict__ X,
                                                     const int* __restrict__ esrc,
                                                     const int* __restrict__ seg,
                                                     const float* __restrict__ norm_dst,
                                                     const float* __restrict__ bias,
                                                     float* __restrict__ out, int N) {
    const int node = blockIdx.x * 4 + (threadIdx.x >> 6);
    const int lane = threadIdx.x & 63;
    if (node >= N) return;
    const int eh = lane >> 4;          // edge slot 0..3
    const int fl = lane & 15;          // feature group
    const int s0 = seg[node];
    const int s1 = seg[node + 1];
    const unsigned short* Xf = X + fl * 4;
    f32x2 A0 = {0.0f, 0.0f};
    f32x2 A1 = {0.0f, 0.0f};
    int e = s0;
    for (; e + 16 <= s1; e += 16) {       // all 16 edges valid: no masking
        const int base = e + eh * 4;
        const int r0 = esrc[base + 0];
        const int r1 = esrc[base + 1];
        const int r2 = esrc[base + 2];
        const int r3 = esrc[base + 3];
        const uint2 u0 = *(const uint2*)&Xf[(size_t)r0 * 64];
        const uint2 u1 = *(const uint2*)&Xf[(size_t)r1 * 64];
        const uint2 u2 = *(const uint2*)&Xf[(size_t)r2 * 64];
        const uint2 u3 = *(const uint2*)&Xf[(size_t)r3 * 64];
        A0 += (f32x2){bflo(u0.x), bfhi(u0.x)}; A1 += (f32x2){bflo(u0.y), bfhi(u0.y)};
        A0 += (f32x2){bflo(u1.x), bfhi(u1.x)}; A1 += (f32x2){bflo(u1.y), bfhi(u1.y)};
        A0 += (f32x2){bflo(u2.x), bfhi(u2.x)}; A1 += (f32x2){bflo(u2.y), bfhi(u2.y)};
        A0 += (f32x2){bflo(u3.x), bfhi(u3.x)}; A1 += (f32x2){bflo(u3.y), bfhi(u3.y)};
    }
    if (e < s1) {                         // single masked tail (redirect to zero row)
        const int base = e + eh * 4;
        const int i0 = esrc[base + 0];    // may over-read <=15 ints: esrc is padded
        const int i1 = esrc[base + 1];
        const int i2 = esrc[base + 2];
        const int i3 = esrc[base + 3];
        const int r0 = (base + 0 < s1) ? i0 : N;
        const int r1 = (base + 1 < s1) ? i1 : N;
        const int r2 = (base + 2 < s1) ? i2 : N;
        const int r3 = (base + 3 < s1) ? i3 : N;
        const uint2 u0 = *(const uint2*)&Xf[(size_t)r0 * 64];
        const uint2 u1 = *(const uint2*)&Xf[(size_t)r1 * 64];
        const uint2 u2 = *(const uint2*)&Xf[(size_t)r2 * 64];
        const uint2 u3 = *(const uint2*)&Xf[(size_t)r3 * 64];
        A0 += (f32x2){bflo(u0.x), bfhi(u0.x)}; A1 += (f32x2){bflo(u0.y), bfhi(u0.y)};
        A0 += (f32x2){bflo(u1.x), bfhi(u1.x)}; A1 += (f32x2){bflo(u1.y), bfhi(u1.y)};
        A0 += (f32x2){bflo(u2.x), bfhi(u2.x)}; A1 += (f32x2){bflo(u2.y), bfhi(u2.y)};
        A0 += (f32x2){bflo(u3.x), bfhi(u3.x)}; A1 += (f32x2){bflo(u3.y), bfhi(u3.y)};
    }
    float a0 = A0.x, a1 = A0.y, a2 = A1.x, a3 = A1.y;
    a0 += __shfl(a0, lane ^ 16); a1 += __shfl(a1, lane ^ 16);
    a2 += __shfl(a2, lane ^ 16); a3 += __shfl(a3, lane ^ 16);
    a0 += __shfl(a0, lane ^ 32); a1 += __shfl(a1, lane ^ 32);
    a2 += __shfl(a2, lane ^ 32); a3 += __shfl(a3, lane ^ 32);
    if (eh == 0) {
        const float s = norm_dst[node];
        const float4 bb = *(const float4*)&bias[fl * 4];
        float4 r;
        r.x = a0 * s + bb.x;
        r.y = a1 * s + bb.y;
        r.z = a2 * s + bb.z;
        r.w = a3 * s + bb.w;
        if (ELU) {
            r.x = r.x > 0.0f ? r.x : expm1f(r.x);
            r.y = r.y > 0.0f ? r.y : expm1f(r.y);
            r.z = r.z > 0.0f ? r.z : expm1f(r.z);
            r.w = r.w > 0.0f ? r.w : expm1f(r.w);
        }
        *(float4*)&out[(size_t)node * 64 + fl * 4] = r;
    }
}

extern "C" void kernel_launch(void* const* d_in, const int* in_sizes, int n_in,
                              void* d_out, int out_size, void* d_ws, size_t ws_size,
                              hipStream_t stream) {
    const float* h   = (const float*)d_in[0];
    const int*   src = (const int*)d_in[1];
    const int*   dst = (const int*)d_in[2];
    const float* W1  = (const float*)d_in[3];
    const float* b1  = (const float*)d_in[4];
    const float* W2  = (const float*)d_in[5];
    const float* b2  = (const float*)d_in[6];
    float* out = (float*)d_out;

    const int N = in_sizes[0] / 128;       // 100000
    const int E = in_sizes[1];             // 1600000
    const int nbuk = (N + 511) >> 9;       // 196
    const int B1 = (E + CH - 1) / CH;      // 391
    const int M = 2 * nbuk * B1;

    int* iw = (int*)d_ws;
    int* mat   = iw;
    int* scanb = mat + M;
    int* bsums = scanb + M + 4;
    int* pedge = bsums + 256;              // 2E
    int* esrc  = pedge + 2 * (size_t)E;    // E (+16 pad for segsum over-read)
    int* seg   = esrc + (size_t)E + 16;    // N+1 (+pad)
    float* fw       = (float*)(seg + (size_t)N + 4);
    float* norm_src = fw;
    float* norm_dst = fw + (size_t)N;
    float* H1       = fw + 2 * (size_t)N;              // 64N floats
    unsigned short* Xb = (unsigned short*)(H1 + 64 * (size_t)N);  // 64(N+1) bf16

    // ---- CSR build ----
    p1a_kernel<<<B1, 256, 0, stream>>>(src, dst, mat, E, B1, nbuk);
    const int G = (M + 1023) / 1024;
    scan1_kernel<<<G, 256, 0, stream>>>(mat, scanb, bsums, M);
    scan2_kernel<<<1, 256, 0, stream>>>(bsums, scanb, M, G);
    scan3_kernel<<<G, 256, 0, stream>>>(scanb, bsums, M);
    p1c_kernel<<<B1, 256, 0, stream>>>(src, dst, mat, scanb, pedge, E, B1, nbuk);
    p2s2_kernel<<<2 * nbuk, 512, 0, stream>>>(pedge, scanb, esrc, seg, norm_dst, norm_src,
                                              N, E, B1, nbuk);

    const int segGrid = (N + 3) / 4;

    // ---- layer 1 ----
    gemm_norm<128><<<(N + 63) / 64, 256, 0, stream>>>(h, W1, norm_src, Xb, N);
    segsum_kernel<true><<<segGrid, 256, 0, stream>>>(Xb, esrc, seg, norm_dst, b1, H1, N);

    // ---- layer 2 ----
    gemm_norm<64><<<(N + 63) / 64, 256, 0, stream>>>(H1, W2, norm_src, Xb, N);
    segsum_kernel<false><<<segGrid, 256, 0, stream>>>(Xb, esrc, seg, norm_dst, b2, out, N);
}